// Round 2
// baseline (304.626 us; speedup 1.0000x reference)
//
#include <hip/hip_runtime.h>
#include <stdint.h>

typedef unsigned int  u32;
typedef unsigned short u16;
typedef __bf16 v8bf __attribute__((ext_vector_type(8)));
typedef float  v4f  __attribute__((ext_vector_type(4)));

#define N_INST 256
#define BATCH  128
#define IN_DIM 1024
#define L_DIM  512
#define M_TOT  (N_INST*BATCH)   // 32768
#define NSLICE 8                // 8 colslice-PAIRS (128 pcols each), full K per block

// Fragment-tiled layouts (u16 units). Region = 1 KB = 64 lanes x 16 B.
// A (xb): region = mblk*256 + kt*16 + g*2 + kk   (g=row-group 0..7)
//   lane(q,c): row = mblk*128 + g*16 + c, k = kt*64 + kk*32 + q*8
// B (wpk): region = cs*128 + kt*8 + j*2 + kk     (cs=colslice 0..15, j=0..3)
//   lane(q,c): packed col p = cs*64 + j*16 + c, k = kt*64 + kk*32 + q*8
//   bcol = p>>4 = cs*4+j (even=V, odd=U), l = (bcol>>1)*16 + c
// ws: [0,64MB) xb; [64MB,66MB) wpk; [66MB,67MB) partial [8][M_TOT]
#define XB_BYTES   ((size_t)M_TOT * IN_DIM * 2)
#define WPK_BYTES  ((size_t)1024 * IN_DIM * 2)

__device__ inline u32 f2bf_pk(float a, float b){
  u32 ua = __builtin_bit_cast(u32, a);
  u32 ub = __builtin_bit_cast(u32, b);
  ua = (ua + 0x7FFFu + ((ua >> 16) & 1u)) >> 16;
  ub = (ub + 0x7FFFu + ((ub >> 16) & 1u)) & 0xFFFF0000u;
  return ua | ub;
}

__device__ inline void gl2lds16(const u16* g, u16* l){
  __builtin_amdgcn_global_load_lds(
      (const __attribute__((address_space(1))) u32*)(g),
      (__attribute__((address_space(3))) u32*)(l), 16, 0, 0);
}

#define PREP_XBLKS 16384
__global__ void prep(const float* __restrict__ x, const float* __restrict__ v,
                     const float* __restrict__ u, u16* __restrict__ xb,
                     u16* __restrict__ wpk){
  const int b = blockIdx.x;
  if (b < PREP_XBLKS){
    int t = b * 256 + threadIdx.x;
    int r = t >> 6, l = t & 63;
    int kk = r & 1, i = (r >> 1) & 3, h = (r >> 3) & 1, kt = (r >> 4) & 15, mb = r >> 8;
    int q = l >> 4, c = l & 15;
    int row = mb*128 + h*64 + i*16 + c;
    int k0  = kt*64 + kk*32 + q*8;
    const float* src = x + (size_t)row * IN_DIM + k0;
    float4 a0 = *reinterpret_cast<const float4*>(src);
    float4 a1 = *reinterpret_cast<const float4*>(src + 4);
    uint4 out;
    out.x = f2bf_pk(a0.x, a0.y); out.y = f2bf_pk(a0.z, a0.w);
    out.z = f2bf_pk(a1.x, a1.y); out.w = f2bf_pk(a1.z, a1.w);
    *reinterpret_cast<uint4*>(xb + (size_t)r*512 + l*8) = out;
  } else {
    int t = (b - PREP_XBLKS) * 256 + threadIdx.x;   // 131072 threads
    int r = t >> 6, l = t & 63;
    int kk = r & 1, j = (r >> 1) & 3, kt = (r >> 3) & 15, cs = r >> 7;
    int q = l >> 4, c = l & 15;
    int bcol = cs*4 + j;
    const float* src = (bcol & 1) ? u : v;
    int lcol = (bcol >> 1)*16 + c;
    int k0 = kt*64 + kk*32 + q*8;
    u32 o[4];
#pragma unroll
    for (int ii = 0; ii < 4; ++ii){
      float a  = src[(size_t)(k0 + 2*ii    ) * L_DIM + lcol];
      float bb = src[(size_t)(k0 + 2*ii + 1) * L_DIM + lcol];
      o[ii] = f2bf_pk(a, bb);
    }
    *reinterpret_cast<uint4*>(wpk + (size_t)r*512 + l*8) = make_uint4(o[0], o[1], o[2], o[3]);
  }
}

// ---- gemm_score: 256 rows x 128 pcols per block, kk-granular register pipeline ----
// A: wave-private rows, direct global->reg (L2-hot). B: 2-kt chunks (32 KB) in LDS,
// double-buffered (64 KB total), 1 barrier per chunk.

#define LOADA_K(KT, KK, B_) { const u16* ak_ = awave + (size_t)(KT)*8192 + (KK)*512;  \
  _Pragma("unroll") for (int gi_ = 0; gi_ < 4; ++gi_)                                 \
    afb[B_][gi_] = *reinterpret_cast<const v8bf*>(ak_ + gi_*1024); }

// LDS chunk layout: region rr = cs_loc*16 + ktl*8 + j_l*2 + kk  (32 regions = 32 KB)
#define LOADB_K(BUF, KTL, KK, B_) {                                                   \
  _Pragma("unroll") for (int j_ = 0; j_ < 8; ++j_)                                    \
    bfb[B_][j_] = *reinterpret_cast<const v8bf*>(                                     \
      &Bs[BUF][(((j_>>2)*16) + (KTL)*8 + ((j_&3)*2) + (KK))*512 + lane*8]); }

#define DOMFMA_K(B_) {                                                                \
  _Pragma("unroll") for (int gi_ = 0; gi_ < 4; ++gi_)                                 \
    _Pragma("unroll") for (int j_ = 0; j_ < 8; ++j_)                                  \
      acc[gi_][j_] = __builtin_amdgcn_mfma_f32_16x16x32_bf16(                         \
          afb[B_][gi_], bfb[B_][j_], acc[gi_][j_], 0, 0, 0); }

__launch_bounds__(256, 2)
__global__ void gemm_score(const u16* __restrict__ xb, const u16* __restrict__ wpk,
                           const float* __restrict__ w, float* __restrict__ partial){
  __shared__ __align__(16) u16 Bs[2][32*512];   // 2 x 32 KB

  const int tid  = threadIdx.x;
  const u32 bid  = blockIdx.x;          // 0..1023
  const int xcd  = bid & 7;
  const int slot = bid >> 3;            // 0..127
  const int csp  = slot & 7;            // colslice pair 0..7
  const int mr   = xcd*16 + (slot >> 3);  // 0..127, XCD-local A reuse
  const int mblk0= mr * 2;

  const int lane = tid & 63;
  const int wave = tid >> 6;
  const int q    = lane >> 4;
  const int c    = lane & 15;

  // stage chunk s (kt = 2s, 2s+1; both cs of the pair) into Bs[buf]
  auto stageB = [&](int s, int buf){
#pragma unroll
    for (int it = 0; it < 8; ++it){
      const int rr     = wave*8 + it;       // 0..31
      const int cs_loc = rr >> 4;           // 0..1
      const int rem    = rr & 15;           // ktl*8 + (j_l*2+kk)
      const u16* src = wpk + ((size_t)((csp*2 + cs_loc)*128 + s*16 + rem))*512 + lane*8;
      gl2lds16(src, &Bs[buf][rr*512 + lane*8]);
    }
  };

  // wave -> mblk (wave>>1), row-groups g = (wave&1)*4 .. +3
  const u16* awave = xb + (size_t)(mblk0 + (wave>>1))*131072
                        + (size_t)((wave&1)*4)*1024 + lane*8;

  v8bf afb[2][4];
  v8bf bfb[2][8];
  v4f  acc[4][8];
#pragma unroll
  for (int gi = 0; gi < 4; ++gi)
#pragma unroll
    for (int j = 0; j < 8; ++j)
      acc[gi][j] = (v4f){0.f, 0.f, 0.f, 0.f};

  stageB(0, 0);
  __syncthreads();                // vmcnt(0) drain -> Bs[0] ready
  LOADA_K(0, 0, 0);
  LOADB_K(0, 0, 0, 0);

#pragma unroll 1
  for (int s = 0; s < 8; ++s){
    const int cur = s & 1;
    if (s < 7) stageB(s+1, cur^1);
    // 4 kk-steps per chunk; entering with (ktl=0,kk=0) in reg-buffer 0
    LOADA_K(2*s,   1, 1); LOADB_K(cur, 0, 1, 1); DOMFMA_K(0);  // compute (0,0)
    LOADA_K(2*s+1, 0, 0); LOADB_K(cur, 1, 0, 0); DOMFMA_K(1);  // compute (0,1)
    LOADA_K(2*s+1, 1, 1); LOADB_K(cur, 1, 1, 1); DOMFMA_K(0);  // compute (1,0)
    if (s < 7) LOADA_K(2*s+2, 0, 0);                           // next chunk's (0,0) A
    DOMFMA_K(1);                                               // compute (1,1)
    __syncthreads();    // reads of Bs[cur] done; stage(s+1) drained (vmcnt 0)
    if (s < 7) LOADB_K(cur^1, 0, 0, 0);
  }

  // epilogue: j pairs (2pp, 2pp+1) = (V,U) @ l = csp*64 + pp*16 + c
  const float wl0 = w[csp*64 +      c];
  const float wl1 = w[csp*64 + 16 + c];
  const float wl2 = w[csp*64 + 32 + c];
  const float wl3 = w[csp*64 + 48 + c];
  float* pout = partial + (size_t)csp * M_TOT
              + (size_t)(mblk0 + (wave>>1))*128 + (wave&1)*64;

#pragma unroll
  for (int gi = 0; gi < 4; ++gi){
#pragma unroll
    for (int r = 0; r < 4; ++r){
      float t0 = 2.f / (1.f + __expf(-2.f * acc[gi][0][r])) - 1.f;
      float s0 = 1.f / (1.f + __expf(-acc[gi][1][r]));
      float t1 = 2.f / (1.f + __expf(-2.f * acc[gi][2][r])) - 1.f;
      float s1 = 1.f / (1.f + __expf(-acc[gi][3][r]));
      float t2 = 2.f / (1.f + __expf(-2.f * acc[gi][4][r])) - 1.f;
      float s2 = 1.f / (1.f + __expf(-acc[gi][5][r]));
      float t3 = 2.f / (1.f + __expf(-2.f * acc[gi][6][r])) - 1.f;
      float s3 = 1.f / (1.f + __expf(-acc[gi][7][r]));
      float v2 = t0*s0*wl0 + t1*s1*wl1 + t2*s2*wl2 + t3*s3*wl3;
      v2 += __shfl_xor(v2, 1, 64);
      v2 += __shfl_xor(v2, 2, 64);
      v2 += __shfl_xor(v2, 4, 64);
      v2 += __shfl_xor(v2, 8, 64);
      if (c == 0) pout[gi*16 + q*4 + r] = v2;   // slice-private rows
    }
  }
}

__global__ void softmax_inst(const float* __restrict__ partial, float* __restrict__ out){
  __shared__ float red[N_INST];
  const int b = blockIdx.x;
  const int n = threadIdx.x;
  float s = 0.f;
#pragma unroll
  for (int i = 0; i < NSLICE; ++i) s += partial[(size_t)i * M_TOT + n*BATCH + b];
  red[n] = s; __syncthreads();
  for (int st = N_INST/2; st > 0; st >>= 1){
    if (n < st) red[n] = fmaxf(red[n], red[n + st]);
    __syncthreads();
  }
  float mx = red[0]; __syncthreads();
  float e = __expf(s - mx);
  red[n] = e; __syncthreads();
  for (int st = N_INST/2; st > 0; st >>= 1){
    if (n < st) red[n] += red[n + st];
    __syncthreads();
  }
  out[n*BATCH + b] = e / red[0];
}

extern "C" void kernel_launch(void* const* d_in, const int* in_sizes, int n_in,
                              void* d_out, int out_size, void* d_ws, size_t ws_size,
                              hipStream_t stream) {
  const float* x = (const float*)d_in[0];
  const float* v = (const float*)d_in[1];
  const float* u = (const float*)d_in[2];
  const float* w = (const float*)d_in[3];
  u16*   xb      = (u16*)d_ws;
  u16*   wpk     = (u16*)((char*)d_ws + XB_BYTES);
  float* partial = (float*)((char*)d_ws + XB_BYTES + WPK_BYTES);
  float* out     = (float*)d_out;

  prep<<<dim3(PREP_XBLKS + 512), dim3(256), 0, stream>>>(x, v, u, xb, wpk);
  gemm_score<<<dim3(1024), dim3(256), 0, stream>>>(xb, wpk, w, partial);
  softmax_inst<<<dim3(BATCH), dim3(N_INST), 0, stream>>>(partial, out);
}

// Round 3
// 291.711 us; speedup vs baseline: 1.0443x; 1.0443x over previous
//
#include <hip/hip_runtime.h>
#include <stdint.h>

typedef unsigned int  u32;
typedef unsigned short u16;
typedef __bf16 v8bf __attribute__((ext_vector_type(8)));
typedef float  v4f  __attribute__((ext_vector_type(4)));

#define N_INST 256
#define BATCH  128
#define IN_DIM 1024
#define L_DIM  512
#define M_TOT  (N_INST*BATCH)   // 32768
#define NSLICE 8                // 8 colslice-PAIRS (128 pcols each), full K per block

// Fragment-tiled layouts (u16 units). Region = 1 KB = 64 lanes x 16 B.
// A (xb): region = mblk*256 + kt*16 + g*2 + kk   (g=row-group 0..7)
//   lane(q,c): row = mblk*128 + g*16 + c, k = kt*64 + kk*32 + q*8
// B (wpk): region = cs*128 + kt*8 + j*2 + kk     (cs=colslice 0..15, j=0..3)
//   lane(q,c): packed col p = cs*64 + j*16 + c, k = kt*64 + kk*32 + q*8
//   bcol = p>>4 = cs*4+j (even=V, odd=U), l = (bcol>>1)*16 + c
// ws: [0,64MB) xb; [64MB,66MB) wpk; [66MB,67MB) partial [8][M_TOT]
#define XB_BYTES   ((size_t)M_TOT * IN_DIM * 2)
#define WPK_BYTES  ((size_t)1024 * IN_DIM * 2)

__device__ inline u32 f2bf_pk(float a, float b){
  u32 ua = __builtin_bit_cast(u32, a);
  u32 ub = __builtin_bit_cast(u32, b);
  ua = (ua + 0x7FFFu + ((ua >> 16) & 1u)) >> 16;
  ub = (ub + 0x7FFFu + ((ub >> 16) & 1u)) & 0xFFFF0000u;
  return ua | ub;
}

__device__ inline void gl2lds16(const u16* g, u16* l){
  __builtin_amdgcn_global_load_lds(
      (const __attribute__((address_space(1))) u32*)(g),
      (__attribute__((address_space(3))) u32*)(l), 16, 0, 0);
}

#define PREP_XBLKS 16384
__global__ void prep(const float* __restrict__ x, const float* __restrict__ v,
                     const float* __restrict__ u, u16* __restrict__ xb,
                     u16* __restrict__ wpk){
  const int b = blockIdx.x;
  if (b < PREP_XBLKS){
    int t = b * 256 + threadIdx.x;
    int r = t >> 6, l = t & 63;
    int kk = r & 1, i = (r >> 1) & 3, h = (r >> 3) & 1, kt = (r >> 4) & 15, mb = r >> 8;
    int q = l >> 4, c = l & 15;
    int row = mb*128 + h*64 + i*16 + c;
    int k0  = kt*64 + kk*32 + q*8;
    const float* src = x + (size_t)row * IN_DIM + k0;
    float4 a0 = *reinterpret_cast<const float4*>(src);
    float4 a1 = *reinterpret_cast<const float4*>(src + 4);
    uint4 out;
    out.x = f2bf_pk(a0.x, a0.y); out.y = f2bf_pk(a0.z, a0.w);
    out.z = f2bf_pk(a1.x, a1.y); out.w = f2bf_pk(a1.z, a1.w);
    *reinterpret_cast<uint4*>(xb + (size_t)r*512 + l*8) = out;
  } else {
    int t = (b - PREP_XBLKS) * 256 + threadIdx.x;   // 131072 threads
    int r = t >> 6, l = t & 63;
    int kk = r & 1, j = (r >> 1) & 3, kt = (r >> 3) & 15, cs = r >> 7;
    int q = l >> 4, c = l & 15;
    int bcol = cs*4 + j;
    const float* src = (bcol & 1) ? u : v;
    int lcol = (bcol >> 1)*16 + c;
    int k0 = kt*64 + kk*32 + q*8;
    u32 o[4];
#pragma unroll
    for (int ii = 0; ii < 4; ++ii){
      float a  = src[(size_t)(k0 + 2*ii    ) * L_DIM + lcol];
      float bb = src[(size_t)(k0 + 2*ii + 1) * L_DIM + lcol];
      o[ii] = f2bf_pk(a, bb);
    }
    *reinterpret_cast<uint4*>(wpk + (size_t)r*512 + l*8) = make_uint4(o[0], o[1], o[2], o[3]);
  }
}

// ---- gemm_score: 256 rows x 128 pcols per block ----
// A: wave-private rows, direct global->reg (L2-hot), double-buffered afb.
// B: 2-kt chunks (32 KB) in LDS, double-buffered (64 KB), 1 barrier per chunk.
// bfb SINGLE-buffered (reg budget): j-outer MFMA order frees bfb[j] after 4 MFMAs,
// next kk-step's ds_read into the same reg interleaved per-j.
// Reg budget: acc 128 + afb 32 + bfb 32 + temps ~ 210 < 256 (2 waves/SIMD) -> no spill.

#define LOADA_K(KT, KK, B_) { const u16* ak_ = awave + (size_t)(KT)*8192 + (KK)*512;  \
  _Pragma("unroll") for (int gi_ = 0; gi_ < 4; ++gi_)                                 \
    afb[B_][gi_] = *reinterpret_cast<const v8bf*>(ak_ + gi_*1024); }

// LDS chunk layout: region rr = cs_loc*16 + ktl*8 + j_l*2 + kk  (32 regions = 32 KB)
#define LOADB_ALL(BUF, KTL, KK) {                                                     \
  _Pragma("unroll") for (int j_ = 0; j_ < 8; ++j_)                                    \
    bfb[j_] = *reinterpret_cast<const v8bf*>(                                         \
      &Bs[BUF][(((j_>>2)*16) + (KTL)*8 + ((j_&3)*2) + (KK))*512 + lane*8]); }

// Compute one kk-step with afb[AB]; if DO_B, refill bfb[j] for next (NKTL,NKK) right
// after its last MFMA reader.
#define STEP_K(AB, DO_B, BUF, NKTL, NKK) {                                            \
  _Pragma("unroll") for (int j_ = 0; j_ < 8; ++j_){                                   \
    _Pragma("unroll") for (int gi_ = 0; gi_ < 4; ++gi_)                               \
      acc[gi_][j_] = __builtin_amdgcn_mfma_f32_16x16x32_bf16(                         \
          afb[AB][gi_], bfb[j_], acc[gi_][j_], 0, 0, 0);                              \
    if (DO_B) bfb[j_] = *reinterpret_cast<const v8bf*>(                               \
      &Bs[BUF][(((j_>>2)*16) + (NKTL)*8 + ((j_&3)*2) + (NKK))*512 + lane*8]);         \
  } }

__launch_bounds__(256, 2)
__global__ void gemm_score(const u16* __restrict__ xb, const u16* __restrict__ wpk,
                           const float* __restrict__ w, float* __restrict__ partial){
  __shared__ __align__(16) u16 Bs[2][32*512];   // 2 x 32 KB

  const int tid  = threadIdx.x;
  const u32 bid  = blockIdx.x;          // 0..1023
  const int xcd  = bid & 7;
  const int slot = bid >> 3;            // 0..127
  const int csp  = slot & 7;            // colslice pair 0..7
  const int mr   = xcd*16 + (slot >> 3);  // 0..127, XCD-local A reuse
  const int mblk0= mr * 2;

  const int lane = tid & 63;
  const int wave = tid >> 6;
  const int q    = lane >> 4;
  const int c    = lane & 15;

  // stage chunk s (kt = 2s, 2s+1; both cs of the pair) into Bs[buf]
  auto stageB = [&](int s, int buf){
#pragma unroll
    for (int it = 0; it < 8; ++it){
      const int rr     = wave*8 + it;       // 0..31
      const int cs_loc = rr >> 4;           // 0..1
      const int rem    = rr & 15;           // ktl*8 + (j_l*2+kk)
      const u16* src = wpk + ((size_t)((csp*2 + cs_loc)*128 + s*16 + rem))*512 + lane*8;
      gl2lds16(src, &Bs[buf][rr*512 + lane*8]);
    }
  };

  // wave -> mblk (wave>>1), row-groups g = (wave&1)*4 .. +3
  const u16* awave = xb + (size_t)(mblk0 + (wave>>1))*131072
                        + (size_t)((wave&1)*4)*1024 + lane*8;

  v8bf afb[2][4];
  v8bf bfb[8];
  v4f  acc[4][8];
#pragma unroll
  for (int gi = 0; gi < 4; ++gi)
#pragma unroll
    for (int j = 0; j < 8; ++j)
      acc[gi][j] = (v4f){0.f, 0.f, 0.f, 0.f};

  stageB(0, 0);
  __syncthreads();                // vmcnt(0) drain -> Bs[0] ready
  LOADA_K(0, 0, 0);
  LOADB_ALL(0, 0, 0);

#pragma unroll 1
  for (int s = 0; s < 8; ++s){
    const int cur = s & 1;
    if (s < 7) stageB(s+1, cur^1);
    // 4 kk-steps per chunk; entering with A(2s,kk0) in afb[0], B(ktl0,kk0) in bfb
    LOADA_K(2*s,   1, 1); STEP_K(0, 1, cur, 0, 1);   // compute (0,0); bfb <- (0,1)
    LOADA_K(2*s+1, 0, 0); STEP_K(1, 1, cur, 1, 0);   // compute (0,1); bfb <- (1,0)
    LOADA_K(2*s+1, 1, 1); STEP_K(0, 1, cur, 1, 1);   // compute (1,0); bfb <- (1,1)
    if (s < 7) LOADA_K(2*s+2, 0, 0);                 // next chunk's (0,0) A
    STEP_K(1, 0, cur, 0, 0);                         // compute (1,1); no bfb refill
    __syncthreads();    // reads of Bs[cur] done; stage(s+1) drained (vmcnt 0)
    if (s < 7) LOADB_ALL(cur^1, 0, 0);
  }

  // epilogue: j pairs (2pp, 2pp+1) = (V,U) @ l = csp*64 + pp*16 + c
  const float wl0 = w[csp*64 +      c];
  const float wl1 = w[csp*64 + 16 + c];
  const float wl2 = w[csp*64 + 32 + c];
  const float wl3 = w[csp*64 + 48 + c];
  float* pout = partial + (size_t)csp * M_TOT
              + (size_t)(mblk0 + (wave>>1))*128 + (wave&1)*64;

#pragma unroll
  for (int gi = 0; gi < 4; ++gi){
#pragma unroll
    for (int r = 0; r < 4; ++r){
      float t0 = 2.f / (1.f + __expf(-2.f * acc[gi][0][r])) - 1.f;
      float s0 = 1.f / (1.f + __expf(-acc[gi][1][r]));
      float t1 = 2.f / (1.f + __expf(-2.f * acc[gi][2][r])) - 1.f;
      float s1 = 1.f / (1.f + __expf(-acc[gi][3][r]));
      float t2 = 2.f / (1.f + __expf(-2.f * acc[gi][4][r])) - 1.f;
      float s2 = 1.f / (1.f + __expf(-acc[gi][5][r]));
      float t3 = 2.f / (1.f + __expf(-2.f * acc[gi][6][r])) - 1.f;
      float s3 = 1.f / (1.f + __expf(-acc[gi][7][r]));
      float v2 = t0*s0*wl0 + t1*s1*wl1 + t2*s2*wl2 + t3*s3*wl3;
      v2 += __shfl_xor(v2, 1, 64);
      v2 += __shfl_xor(v2, 2, 64);
      v2 += __shfl_xor(v2, 4, 64);
      v2 += __shfl_xor(v2, 8, 64);
      if (c == 0) pout[gi*16 + q*4 + r] = v2;   // slice-private rows
    }
  }
}

__global__ void softmax_inst(const float* __restrict__ partial, float* __restrict__ out){
  __shared__ float red[N_INST];
  const int b = blockIdx.x;
  const int n = threadIdx.x;
  float s = 0.f;
#pragma unroll
  for (int i = 0; i < NSLICE; ++i) s += partial[(size_t)i * M_TOT + n*BATCH + b];
  red[n] = s; __syncthreads();
  for (int st = N_INST/2; st > 0; st >>= 1){
    if (n < st) red[n] = fmaxf(red[n], red[n + st]);
    __syncthreads();
  }
  float mx = red[0]; __syncthreads();
  float e = __expf(s - mx);
  red[n] = e; __syncthreads();
  for (int st = N_INST/2; st > 0; st >>= 1){
    if (n < st) red[n] += red[n + st];
    __syncthreads();
  }
  out[n*BATCH + b] = e / red[0];
}

extern "C" void kernel_launch(void* const* d_in, const int* in_sizes, int n_in,
                              void* d_out, int out_size, void* d_ws, size_t ws_size,
                              hipStream_t stream) {
  const float* x = (const float*)d_in[0];
  const float* v = (const float*)d_in[1];
  const float* u = (const float*)d_in[2];
  const float* w = (const float*)d_in[3];
  u16*   xb      = (u16*)d_ws;
  u16*   wpk     = (u16*)((char*)d_ws + XB_BYTES);
  float* partial = (float*)((char*)d_ws + XB_BYTES + WPK_BYTES);
  float* out     = (float*)d_out;

  prep<<<dim3(PREP_XBLKS + 512), dim3(256), 0, stream>>>(x, v, u, xb, wpk);
  gemm_score<<<dim3(1024), dim3(256), 0, stream>>>(xb, wpk, w, partial);
  softmax_inst<<<dim3(BATCH), dim3(N_INST), 0, stream>>>(partial, out);
}

// Round 4
// 283.214 us; speedup vs baseline: 1.0756x; 1.0300x over previous
//
#include <hip/hip_runtime.h>
#include <stdint.h>

typedef unsigned int  u32;
typedef unsigned short u16;
typedef __bf16 v8bf __attribute__((ext_vector_type(8)));
typedef float  v4f  __attribute__((ext_vector_type(4)));

#define N_INST 256
#define BATCH  128
#define IN_DIM 1024
#define L_DIM  512
#define M_TOT  (N_INST*BATCH)   // 32768
#define NSLICE 16               // 16 colslices (64 pcols each), full K per block

// Fragment-tiled layouts (u16 units). Region = 1 KB = 64 lanes x 16 B.
// A (xb): region = mblk*256 + kt*16 + g*2 + kk   (g=row-group 0..7)
//   lane(q,c): row = mblk*128 + g*16 + c, k = kt*64 + kk*32 + q*8
// B (wpk): region = cs*128 + kt*8 + j*2 + kk     (cs=colslice 0..15, j=0..3)
//   lane(q,c): packed col p = cs*64 + j*16 + c, k = kt*64 + kk*32 + q*8
//   bcol = p>>4 = cs*4+j (even=V, odd=U), l = (bcol>>1)*16 + c
// ws: [0,64MB) xb; [64MB,66MB) wpk; [66MB,68MB) partial [16][M_TOT]
#define XB_BYTES   ((size_t)M_TOT * IN_DIM * 2)
#define WPK_BYTES  ((size_t)1024 * IN_DIM * 2)

__device__ inline u32 f2bf_pk(float a, float b){
  u32 ua = __builtin_bit_cast(u32, a);
  u32 ub = __builtin_bit_cast(u32, b);
  ua = (ua + 0x7FFFu + ((ua >> 16) & 1u)) >> 16;
  ub = (ub + 0x7FFFu + ((ub >> 16) & 1u)) & 0xFFFF0000u;
  return ua | ub;
}

__device__ inline void gl2lds16(const u16* g, u16* l){
  __builtin_amdgcn_global_load_lds(
      (const __attribute__((address_space(1))) u32*)(g),
      (__attribute__((address_space(3))) u32*)(l), 16, 0, 0);
}

#define PREP_XBLKS 16384
__global__ void prep(const float* __restrict__ x, const float* __restrict__ v,
                     const float* __restrict__ u, u16* __restrict__ xb,
                     u16* __restrict__ wpk){
  const int b = blockIdx.x;
  if (b < PREP_XBLKS){
    int t = b * 256 + threadIdx.x;
    int r = t >> 6, l = t & 63;
    int kk = r & 1, i = (r >> 1) & 3, h = (r >> 3) & 1, kt = (r >> 4) & 15, mb = r >> 8;
    int q = l >> 4, c = l & 15;
    int row = mb*128 + h*64 + i*16 + c;
    int k0  = kt*64 + kk*32 + q*8;
    const float* src = x + (size_t)row * IN_DIM + k0;
    float4 a0 = *reinterpret_cast<const float4*>(src);
    float4 a1 = *reinterpret_cast<const float4*>(src + 4);
    uint4 out;
    out.x = f2bf_pk(a0.x, a0.y); out.y = f2bf_pk(a0.z, a0.w);
    out.z = f2bf_pk(a1.x, a1.y); out.w = f2bf_pk(a1.z, a1.w);
    *reinterpret_cast<uint4*>(xb + (size_t)r*512 + l*8) = out;
  } else {
    int t = (b - PREP_XBLKS) * 256 + threadIdx.x;   // 131072 threads
    int r = t >> 6, l = t & 63;
    int kk = r & 1, j = (r >> 1) & 3, kt = (r >> 3) & 15, cs = r >> 7;
    int q = l >> 4, c = l & 15;
    int bcol = cs*4 + j;
    const float* src = (bcol & 1) ? u : v;
    int lcol = (bcol >> 1)*16 + c;
    int k0 = kt*64 + kk*32 + q*8;
    u32 o[4];
#pragma unroll
    for (int ii = 0; ii < 4; ++ii){
      float a  = src[(size_t)(k0 + 2*ii    ) * L_DIM + lcol];
      float bb = src[(size_t)(k0 + 2*ii + 1) * L_DIM + lcol];
      o[ii] = f2bf_pk(a, bb);
    }
    *reinterpret_cast<uint4*>(wpk + (size_t)r*512 + l*8) = make_uint4(o[0], o[1], o[2], o[3]);
  }
}

// ---- gemm_score: 256 rows x 64 pcols per block, lean registers for 3 waves/SIMD ----
// acc[4][4]=64 + afb[2][4]=32 (dbuf) + bfb[4]=16 (single, j-outer refill) = 112 decl.
// __launch_bounds__(256,3) caps total (VGPR+AGPR unified) at 170 -> 3 blocks/CU,
// 12 waves/CU. B: 2-kt chunks (16 KB) in LDS, double-buffered (32 KB), 1 barrier/chunk.

#define LOADA_K(KT, KK, B_) { const u16* ak_ = awave + (size_t)(KT)*8192 + (KK)*512;  \
  _Pragma("unroll") for (int gi_ = 0; gi_ < 4; ++gi_)                                 \
    afb[B_][gi_] = *reinterpret_cast<const v8bf*>(ak_ + gi_*1024); }

// LDS chunk layout: region rr = ktl*8 + j*2 + kk (16 regions = 16 KB)
#define LOADB_ALL(BUF, KTL, KK) {                                                     \
  _Pragma("unroll") for (int j_ = 0; j_ < 4; ++j_)                                    \
    bfb[j_] = *reinterpret_cast<const v8bf*>(                                         \
      &Bs[BUF][((KTL)*8 + j_*2 + (KK))*512 + lane*8]); }

// Compute one kk-step with afb[AB]; if DO_B, refill bfb[j] for next (NKTL,NKK) right
// after its last MFMA reader.
#define STEP_K(AB, DO_B, BUF, NKTL, NKK) {                                            \
  _Pragma("unroll") for (int j_ = 0; j_ < 4; ++j_){                                   \
    _Pragma("unroll") for (int gi_ = 0; gi_ < 4; ++gi_)                               \
      acc[gi_][j_] = __builtin_amdgcn_mfma_f32_16x16x32_bf16(                         \
          afb[AB][gi_], bfb[j_], acc[gi_][j_], 0, 0, 0);                              \
    if (DO_B) bfb[j_] = *reinterpret_cast<const v8bf*>(                               \
      &Bs[BUF][((NKTL)*8 + j_*2 + (NKK))*512 + lane*8]);                              \
  } }

__launch_bounds__(256, 3)
__global__ void gemm_score(const u16* __restrict__ xb, const u16* __restrict__ wpk,
                           const float* __restrict__ w, float* __restrict__ partial){
  __shared__ __align__(16) u16 Bs[2][16*512];   // 2 x 16 KB

  const int tid  = threadIdx.x;
  const u32 bid  = blockIdx.x;          // 0..2047
  const int xcd  = bid & 7;
  const int slot = bid >> 3;            // 0..255
  const int cs   = slot & 15;
  const int mr   = xcd*16 + (slot >> 4);  // 0..127, XCD-local A reuse
  const int mblk0= mr * 2;

  const int lane = tid & 63;
  const int wave = tid >> 6;
  const int q    = lane >> 4;
  const int c    = lane & 15;

  // stage chunk s (kt = 2s, 2s+1) into Bs[buf]: 16 regions, 4 per wave
  auto stageB = [&](int s, int buf){
#pragma unroll
    for (int it = 0; it < 4; ++it){
      const int rr = wave*4 + it;           // 0..15 = ktl*8 + j*2 + kk
      const u16* src = wpk + ((size_t)(cs*128 + s*16 + rr))*512 + lane*8;
      gl2lds16(src, &Bs[buf][rr*512 + lane*8]);
    }
  };

  // wave -> mblk (wave>>1), row-groups g = (wave&1)*4 .. +3
  const u16* awave = xb + (size_t)(mblk0 + (wave>>1))*131072
                        + (size_t)((wave&1)*4)*1024 + lane*8;

  v8bf afb[2][4];
  v8bf bfb[4];
  v4f  acc[4][4];
#pragma unroll
  for (int gi = 0; gi < 4; ++gi)
#pragma unroll
    for (int j = 0; j < 4; ++j)
      acc[gi][j] = (v4f){0.f, 0.f, 0.f, 0.f};

  stageB(0, 0);
  __syncthreads();                // vmcnt(0) drain -> Bs[0] ready
  LOADA_K(0, 0, 0);
  LOADB_ALL(0, 0, 0);

#pragma unroll 1
  for (int s = 0; s < 8; ++s){
    const int cur = s & 1;
    if (s < 7) stageB(s+1, cur^1);
    // 4 kk-steps per chunk; entering with A(2s,kk0) in afb[0], B(ktl0,kk0) in bfb
    LOADA_K(2*s,   1, 1); STEP_K(0, 1, cur, 0, 1);   // compute (0,0); bfb <- (0,1)
    LOADA_K(2*s+1, 0, 0); STEP_K(1, 1, cur, 1, 0);   // compute (0,1); bfb <- (1,0)
    LOADA_K(2*s+1, 1, 1); STEP_K(0, 1, cur, 1, 1);   // compute (1,0); bfb <- (1,1)
    if (s < 7) LOADA_K(2*s+2, 0, 0);                 // next chunk's (0,0) A
    STEP_K(1, 0, cur, 0, 0);                         // compute (1,1); no bfb refill
    __syncthreads();    // reads of Bs[cur] done; stage(s+1) drained (vmcnt 0)
    if (s < 7) LOADB_ALL(cur^1, 0, 0);
  }

  // epilogue: j pairs (0,1)=V,U @ l=cs*32+c ; (2,3)=V,U @ +16
  const float wl0 = w[cs*32 + c];
  const float wl1 = w[cs*32 + 16 + c];
  float* pout = partial + (size_t)cs * M_TOT
              + (size_t)(mblk0 + (wave>>1))*128 + (wave&1)*64;

#pragma unroll
  for (int gi = 0; gi < 4; ++gi){
#pragma unroll
    for (int r = 0; r < 4; ++r){
      float t0 = 2.f / (1.f + __expf(-2.f * acc[gi][0][r])) - 1.f;
      float s0 = 1.f / (1.f + __expf(-acc[gi][1][r]));
      float t1 = 2.f / (1.f + __expf(-2.f * acc[gi][2][r])) - 1.f;
      float s1 = 1.f / (1.f + __expf(-acc[gi][3][r]));
      float v2 = t0*s0*wl0 + t1*s1*wl1;
      v2 += __shfl_xor(v2, 1, 64);
      v2 += __shfl_xor(v2, 2, 64);
      v2 += __shfl_xor(v2, 4, 64);
      v2 += __shfl_xor(v2, 8, 64);
      if (c == 0) pout[gi*16 + q*4 + r] = v2;   // slice-private rows
    }
  }
}

__global__ void softmax_inst(const float* __restrict__ partial, float* __restrict__ out){
  __shared__ float red[N_INST];
  const int b = blockIdx.x;
  const int n = threadIdx.x;
  float s = 0.f;
#pragma unroll
  for (int i = 0; i < NSLICE; ++i) s += partial[(size_t)i * M_TOT + n*BATCH + b];
  red[n] = s; __syncthreads();
  for (int st = N_INST/2; st > 0; st >>= 1){
    if (n < st) red[n] = fmaxf(red[n], red[n + st]);
    __syncthreads();
  }
  float mx = red[0]; __syncthreads();
  float e = __expf(s - mx);
  red[n] = e; __syncthreads();
  for (int st = N_INST/2; st > 0; st >>= 1){
    if (n < st) red[n] += red[n + st];
    __syncthreads();
  }
  out[n*BATCH + b] = e / red[0];
}

extern "C" void kernel_launch(void* const* d_in, const int* in_sizes, int n_in,
                              void* d_out, int out_size, void* d_ws, size_t ws_size,
                              hipStream_t stream) {
  const float* x = (const float*)d_in[0];
  const float* v = (const float*)d_in[1];
  const float* u = (const float*)d_in[2];
  const float* w = (const float*)d_in[3];
  u16*   xb      = (u16*)d_ws;
  u16*   wpk     = (u16*)((char*)d_ws + XB_BYTES);
  float* partial = (float*)((char*)d_ws + XB_BYTES + WPK_BYTES);
  float* out     = (float*)d_out;

  prep<<<dim3(PREP_XBLKS + 512), dim3(256), 0, stream>>>(x, v, u, xb, wpk);
  gemm_score<<<dim3(2048), dim3(256), 0, stream>>>(xb, wpk, w, partial);
  softmax_inst<<<dim3(BATCH), dim3(N_INST), 0, stream>>>(partial, out);
}